// Round 1
// baseline (43.185 us; speedup 1.0000x reference)
//
#include <hip/hip_runtime.h>

// Problem constants (from reference setup_inputs)
#define BB 4
#define CC 128
#define HH 192
#define WW 256
#define HW (HH * WW)

// Pass 1: per-pixel channel reductions -> normalized dot-product map D[b,h,w].
// Block = one (b,h) row: 256 threads = 64 pixel-quads (float4 along W) x 4
// channel chunks of 32 channels. LDS reduce across the 4 chunks.
__global__ __launch_bounds__(256) void dotnorm_kernel(
    const float* __restrict__ img, const float* __restrict__ evt,
    float* __restrict__ D)
{
    const int row = blockIdx.x;          // b*H + h
    const int tid = threadIdx.x;
    const int qx  = tid & 63;            // pixel quad within the row
    const int cz  = tid >> 6;            // channel chunk 0..3 (== wave id)
    const int b   = row / HH;
    const int h   = row - b * HH;
    const int w0  = qx << 2;
    const int base0 = b * CC * HW + h * WW + w0;   // offset at c=0 (fits int)
    const int c0  = cz * 32;

    float4 aii = make_float4(0.f, 0.f, 0.f, 0.f);
    float4 aee = make_float4(0.f, 0.f, 0.f, 0.f);
    float4 aie = make_float4(0.f, 0.f, 0.f, 0.f);

    #pragma unroll 8
    for (int c = 0; c < 32; ++c) {
        const float4 iv = *reinterpret_cast<const float4*>(img + base0 + (c0 + c) * HW);
        const float4 ev = *reinterpret_cast<const float4*>(evt + base0 + (c0 + c) * HW);
        aii.x += iv.x * iv.x; aii.y += iv.y * iv.y; aii.z += iv.z * iv.z; aii.w += iv.w * iv.w;
        aee.x += ev.x * ev.x; aee.y += ev.y * ev.y; aee.z += ev.z * ev.z; aee.w += ev.w * ev.w;
        aie.x += iv.x * ev.x; aie.y += iv.y * ev.y; aie.z += iv.z * ev.z; aie.w += iv.w * ev.w;
    }

    __shared__ float s_ii[4][256];
    __shared__ float s_ee[4][256];
    __shared__ float s_ie[4][256];
    const int p4 = qx << 2;
    s_ii[cz][p4 + 0] = aii.x; s_ii[cz][p4 + 1] = aii.y; s_ii[cz][p4 + 2] = aii.z; s_ii[cz][p4 + 3] = aii.w;
    s_ee[cz][p4 + 0] = aee.x; s_ee[cz][p4 + 1] = aee.y; s_ee[cz][p4 + 2] = aee.z; s_ee[cz][p4 + 3] = aee.w;
    s_ie[cz][p4 + 0] = aie.x; s_ie[cz][p4 + 1] = aie.y; s_ie[cz][p4 + 2] = aie.z; s_ie[cz][p4 + 3] = aie.w;
    __syncthreads();

    // Thread t finalizes pixel t of this row (conflict-free: consecutive addrs).
    const float ii = s_ii[0][tid] + s_ii[1][tid] + s_ii[2][tid] + s_ii[3][tid];
    const float ee = s_ee[0][tid] + s_ee[1][tid] + s_ee[2][tid] + s_ee[3][tid];
    const float ie = s_ie[0][tid] + s_ie[1][tid] + s_ie[2][tid] + s_ie[3][tid];
    const float ni = fmaxf(sqrtf(ii), 1e-12f);
    const float ne = fmaxf(sqrtf(ee), 1e-12f);
    D[row * WW + tid] = ie / (ni * ne);
}

// Pass 2: out[b,k=(i,j),h,w] = max(D[b, h+i-1, w+j-1], 0), zero outside.
// One thread per float4 of output width; all 9 k-planes written per thread.
__global__ __launch_bounds__(256) void gather_kernel(
    const float* __restrict__ D, float* __restrict__ out)
{
    const int idx = blockIdx.x * 256 + threadIdx.x;   // 0 .. B*H*W/4 - 1
    const int qx  = idx & 63;
    const int rh  = idx >> 6;            // b*H + h
    const int b   = rh / HH;
    const int h   = rh - b * HH;
    const int w0  = qx << 2;

    float r[3][6];
    #pragma unroll
    for (int dy = 0; dy < 3; ++dy) {
        const int y = h + dy - 1;
        const bool vy = (y >= 0) && (y < HH);
        const int rowbase = (b * HH + y) * WW;
        #pragma unroll
        for (int x = 0; x < 6; ++x) {
            const int xx = w0 + x - 1;
            r[dy][x] = (vy && xx >= 0 && xx < WW) ? D[rowbase + xx] : 0.0f;
        }
    }

    #pragma unroll
    for (int i = 0; i < 3; ++i) {
        #pragma unroll
        for (int j = 0; j < 3; ++j) {
            float4 o;
            o.x = fmaxf(r[i][j + 0], 0.0f);
            o.y = fmaxf(r[i][j + 1], 0.0f);
            o.z = fmaxf(r[i][j + 2], 0.0f);
            o.w = fmaxf(r[i][j + 3], 0.0f);
            const int k = i * 3 + j;
            *reinterpret_cast<float4*>(out + (((b * 9 + k) * HH + h) * WW + w0)) = o;
        }
    }
}

extern "C" void kernel_launch(void* const* d_in, const int* in_sizes, int n_in,
                              void* d_out, int out_size, void* d_ws, size_t ws_size,
                              hipStream_t stream) {
    const float* img = (const float*)d_in[0];
    const float* evt = (const float*)d_in[1];
    float* out = (float*)d_out;
    float* D   = (float*)d_ws;   // needs B*H*W*4 = 3,145,728 bytes

    dotnorm_kernel<<<BB * HH, 256, 0, stream>>>(img, evt, D);
    gather_kernel<<<(BB * HH * WW / 4) / 256, 256, 0, stream>>>(D, out);
}

// Round 2
// 38.856 us; speedup vs baseline: 1.1114x; 1.1114x over previous
//
#include <hip/hip_runtime.h>

// Problem constants (from reference setup_inputs)
#define BB 4
#define CC 128
#define HH 192
#define WW 256
#define HW (HH * WW)

// Pass 1: per-pixel channel reductions -> normalized dot map D[b,h,w].
// Block = 64 pixels (16 float4-quads) x 16 channel-chunks of 8 channels.
// Grid = B*H*(W/64) = 3072 blocks -> 12 blocks/CU available (8 resident = 100% occ).
__global__ __launch_bounds__(256) void dotnorm_kernel(
    const float* __restrict__ img, const float* __restrict__ evt,
    float* __restrict__ D)
{
    const int blk = blockIdx.x;            // (b*H + h)*4 + seg
    const int tid = threadIdx.x;
    const int qx  = tid & 15;              // quad within 64-pixel segment
    const int cz  = tid >> 4;              // channel chunk 0..15
    const int seg = blk & 3;
    const int row = blk >> 2;              // b*H + h
    const int b   = row / HH;
    const int h   = row - b * HH;
    const int w0  = seg * 64 + (qx << 2);
    const int base0 = b * CC * HW + h * WW + w0;   // offset at c=0 (< 2^25)
    const int cbase = cz * 8;

    float4 aii = make_float4(0.f, 0.f, 0.f, 0.f);
    float4 aee = make_float4(0.f, 0.f, 0.f, 0.f);
    float4 aie = make_float4(0.f, 0.f, 0.f, 0.f);

    #pragma unroll
    for (int c = 0; c < 8; ++c) {
        const float4 iv = *reinterpret_cast<const float4*>(img + base0 + (cbase + c) * HW);
        const float4 ev = *reinterpret_cast<const float4*>(evt + base0 + (cbase + c) * HW);
        aii.x += iv.x * iv.x; aii.y += iv.y * iv.y; aii.z += iv.z * iv.z; aii.w += iv.w * iv.w;
        aee.x += ev.x * ev.x; aee.y += ev.y * ev.y; aee.z += ev.z * ev.z; aee.w += ev.w * ev.w;
        aie.x += iv.x * ev.x; aie.y += iv.y * ev.y; aie.z += iv.z * ev.z; aie.w += iv.w * ev.w;
    }

    __shared__ float s_ii[16][64];
    __shared__ float s_ee[16][64];
    __shared__ float s_ie[16][64];
    const int p4 = qx << 2;
    s_ii[cz][p4 + 0] = aii.x; s_ii[cz][p4 + 1] = aii.y; s_ii[cz][p4 + 2] = aii.z; s_ii[cz][p4 + 3] = aii.w;
    s_ee[cz][p4 + 0] = aee.x; s_ee[cz][p4 + 1] = aee.y; s_ee[cz][p4 + 2] = aee.z; s_ee[cz][p4 + 3] = aee.w;
    s_ie[cz][p4 + 0] = aie.x; s_ie[cz][p4 + 1] = aie.y; s_ie[cz][p4 + 2] = aie.z; s_ie[cz][p4 + 3] = aie.w;
    __syncthreads();

    // Threads 0..63 finalize one pixel each (16 chunk partials; 2-way bank alias = free).
    if (tid < 64) {
        float ii = 0.f, ee = 0.f, ie = 0.f;
        #pragma unroll
        for (int k = 0; k < 16; ++k) {
            ii += s_ii[k][tid];
            ee += s_ee[k][tid];
            ie += s_ie[k][tid];
        }
        const float ni = fmaxf(sqrtf(ii), 1e-12f);
        const float ne = fmaxf(sqrtf(ee), 1e-12f);
        D[row * WW + seg * 64 + tid] = ie / (ni * ne);
    }
}

// Pass 2: out[b,k=(i,j),h,w] = max(D[b, h+i-1, w+j-1], 0), zero outside.
// One thread per output float4; grid = B*9*H*W/4/256 = 1728 blocks.
__global__ __launch_bounds__(256) void gather_kernel(
    const float* __restrict__ D, float* __restrict__ out)
{
    const int idx = blockIdx.x * 256 + threadIdx.x;   // output quad index
    const int qx   = idx & 63;
    const int rest = idx >> 6;           // (b*9 + k)*H + h
    const int h    = rest % HH;
    const int bk   = rest / HH;
    const int k    = bk % 9;
    const int b    = bk / 9;
    const int i    = k / 3;
    const int j    = k - 3 * i;
    const int w0   = qx << 2;

    const int y  = h + i - 1;
    const bool vy = (y >= 0) && (y < HH);
    const int rowbase = (b * HH + y) * WW;

    float4 o;
    float* op = &o.x;
    #pragma unroll
    for (int e = 0; e < 4; ++e) {
        const int x = w0 + e + j - 1;
        const float v = (vy && x >= 0 && x < WW) ? D[rowbase + x] : 0.0f;
        op[e] = fmaxf(v, 0.0f);
    }
    *reinterpret_cast<float4*>(out + (size_t)idx * 4) = o;
}

extern "C" void kernel_launch(void* const* d_in, const int* in_sizes, int n_in,
                              void* d_out, int out_size, void* d_ws, size_t ws_size,
                              hipStream_t stream) {
    const float* img = (const float*)d_in[0];
    const float* evt = (const float*)d_in[1];
    float* out = (float*)d_out;
    float* D   = (float*)d_ws;   // needs B*H*W*4 = 3,145,728 bytes

    dotnorm_kernel<<<BB * HH * 4, 256, 0, stream>>>(img, evt, D);
    gather_kernel<<<(BB * 9 * HH * WW / 4) / 256, 256, 0, stream>>>(D, out);
}